// Round 8
// baseline (72.689 us; speedup 1.0000x reference)
//
#include <hip/hip_runtime.h>
#include <math.h>

// SnakeLoss: x,target [B=64, N=1024, 2] fp32.
// shift_means[b,s] = (1/N) sum_j ||x[b,j] - target[b,(j-s)%N]||
// out = mean_b min_s shift_means[b,s]   (scalar fp32)
//
// V8 = V7 (69.2 us best) with JGRP 16->8: halves the partial intermediate
// (4->2 MB: half the min-kernel read + half the partial stores), doubles
// per-block j-work (better staging amortization). 512 blocks = 2/CU,
// 8 waves/CU -- still enough TLP for a loop body with ~104 VALU cyc/iter
// vs one prefetchable ds_read_b128.
// Kept from V7: pk-f32 inner math (t4 staged (t0.x,t1.x,t0.y,t1.y), v2f
// ext-vector ops -> v_pk_*_f32), t shared across G=4 shifts (one
// ds_read_b128 feeds 8 distances), x on scalar/SMEM path, raw v_sqrt_f32,
// plain-store 3-dispatch tail (atomic tails and cooperative launch both
// regressed/failed in V4-V6).

#define BATCH 64
#define NPT   1024
#define TPB   256
#define G     4              // shifts per thread (s = tid + 256g)
#define JGRP  8              // j chunks -> grid = 64*8 = 512 blocks
#define JLEN  (NPT / JGRP)   // 128
#define TWIN  (JLEN + 256)   // 384 window entries (need 383)

typedef float v2f __attribute__((ext_vector_type(2)));

__global__ __launch_bounds__(TPB) void snake_partial(
    const float2* __restrict__ x, const float2* __restrict__ tgt,
    float* __restrict__ partial) {
  const int b   = blockIdx.x;
  const int jg  = blockIdx.y;
  const int tid = threadIdx.x;
  const int j0  = jg * JLEN;

  // t4[w] = (t[w].x, t[w+1].x, t[w].y, t[w+1].y), t[w] = tgt[b][(kb+w)%N].
  __shared__ float4 t4[TWIN];
  const float2* tb = tgt + b * NPT;
  const int kb = (j0 - 255) & (NPT - 1);
  for (int w = tid; w < TWIN; w += TPB) {
    const float2 a = tb[(kb + w) & (NPT - 1)];
    const float2 c = tb[(kb + w + 1) & (NPT - 1)];
    t4[w] = make_float4(a.x, c.x, a.y, c.y);
  }
  __syncthreads();

  // x chunk base per group: cg = (j0 + 256g) % N; chunks are 128-long,
  // 128-aligned -> never wrap. Uniform addresses -> scalar loads.
  const float4* xg[G];
#pragma unroll
  for (int g = 0; g < G; ++g) {
    const int cg = (j0 + 256 * g) & (NPT - 1);
    xg[g] = (const float4*)(x + b * NPT + cg);
  }

  v2f acc[G];
#pragma unroll
  for (int g = 0; g < G; ++g) acc[g] = (v2f){0.f, 0.f};

  const int off0 = 255 - tid;  // t4[off0+jl] covers j=j0+jl, j0+jl+1 at shift tid
#pragma unroll 4
  for (int jl = 0; jl < JLEN; jl += 2) {
    const float4 tp = t4[off0 + jl];       // one b128 shared by 4 shift groups
    const v2f Tx = {tp.x, tp.y};           // (t_j.x,  t_j1.x)
    const v2f Ty = {tp.z, tp.w};           // (t_j.y,  t_j1.y)
#pragma unroll
    for (int g = 0; g < G; ++g) {
      const float4 xp = xg[g][jl >> 1];    // uniform: s_load_dwordx4
      const v2f Xx = {xp.x, xp.z};
      const v2f Xy = {xp.y, xp.w};
      const v2f dX = Xx - Tx;              // v_pk_add_f32 (neg)
      const v2f dY = Xy - Ty;
      const v2f ss = __builtin_elementwise_fma(dX, dX, dY * dY);
      acc[g] += (v2f){__builtin_amdgcn_sqrtf(ss.x),
                      __builtin_amdgcn_sqrtf(ss.y)};
    }
  }

  float* prow = partial + (jg * BATCH + b) * NPT;  // s innermost: coalesced
#pragma unroll
  for (int g = 0; g < G; ++g)
    prow[tid + 256 * g] = acc[g].x + acc[g].y;
}

// grid (BATCH, 4): thread owns shift s = sg*256+tid; sum 8 jg-partials,
// block-min over 256 shifts -> bmin2[b*4+sg]. Plain stores only.
__global__ __launch_bounds__(TPB) void snake_min(
    const float* __restrict__ partial, float* __restrict__ bmin2) {
  const int b   = blockIdx.x;
  const int sg  = blockIdx.y;
  const int tid = threadIdx.x;
  const int s   = sg * TPB + tid;
  float tot = 0.f;
#pragma unroll
  for (int jg = 0; jg < JGRP; ++jg)
    tot += partial[(jg * BATCH + b) * NPT + s];
  float m = tot;
  for (int o = 32; o > 0; o >>= 1)
    m = fminf(m, __shfl_down(m, o));
  __shared__ float red[4];
  if ((tid & 63) == 0) red[tid >> 6] = m;
  __syncthreads();
  if (tid == 0)
    bmin2[b * 4 + sg] = fminf(fminf(red[0], red[1]), fminf(red[2], red[3]));
}

__global__ void snake_final(const float* __restrict__ bmin2,
                            float* __restrict__ out) {
  const int b = threadIdx.x;  // 64 threads = 1 wave
  const float4 bm = ((const float4*)bmin2)[b];
  float v = fminf(fminf(bm.x, bm.y), fminf(bm.z, bm.w));
  for (int o = 32; o > 0; o >>= 1)
    v += __shfl_down(v, o);
  if (b == 0)
    out[0] = v * (1.0f / ((float)NPT * (float)BATCH));
}

extern "C" void kernel_launch(void* const* d_in, const int* in_sizes, int n_in,
                              void* d_out, int out_size, void* d_ws, size_t ws_size,
                              hipStream_t stream) {
  const float2* x   = (const float2*)d_in[0];
  const float2* tgt = (const float2*)d_in[1];
  float* partial = (float*)d_ws;                   // 8*64*1024 floats = 2 MB
  float* bmin2   = partial + JGRP * BATCH * NPT;   // 256 floats
  float* out     = (float*)d_out;

  dim3 g1(BATCH, JGRP);
  snake_partial<<<g1, TPB, 0, stream>>>(x, tgt, partial);
  dim3 g2(BATCH, 4);
  snake_min<<<g2, TPB, 0, stream>>>(partial, bmin2);
  snake_final<<<1, 64, 0, stream>>>(bmin2, out);
}

// Round 9
// 69.009 us; speedup vs baseline: 1.0533x; 1.0533x over previous
//
#include <hip/hip_runtime.h>
#include <math.h>

// SnakeLoss: x,target [B=64, N=1024, 2] fp32.
// shift_means[b,s] = (1/N) sum_j ||x[b,j] - target[b,(j-s)%N]||
// out = mean_b min_s shift_means[b,s]   (scalar fp32)
//
// V9 = V7 verbatim (69.2 us, session best). Confirmation run.
// Ledger: V4/V5 atomic 2-dispatch tail +12us; V6 cooperative launch fails
// in harness; V8 JGRP 8 (512 blocks, 2/CU) +3.5us -- occupancy, not
// intermediate traffic, binds the partial kernel. Fixed 40.4us ws-poison
// fill dominates; partial ~6us sits near its sqrt-bound VALU floor
// (~104 cyc per wave per 8 dists, 64 of them v_sqrt_f32).
// Structure: 3 dispatches, plain stores, single final store to d_out.
//  - t shared across G=4 shifts (thread owns s=tid+256g, processes j offset
//    by 256g -> same t index): one ds_read_b128 feeds 8 distances.
//  - x on the scalar/SMEM path (wave-uniform addresses).
//  - pk-f32 inner math: t4 staged (t0.x,t1.x,t0.y,t1.y), v2f ext-vector ops.
//  - raw v_sqrt_f32 via __builtin_amdgcn_sqrtf (threshold 3.4e-2, ~1 ulp).

#define BATCH 64
#define NPT   1024
#define TPB   256
#define G     4              // shifts per thread (s = tid + 256g)
#define JGRP  16             // j chunks -> grid = 64*16 = 1024 blocks
#define JLEN  (NPT / JGRP)   // 64
#define TWIN  (JLEN + 256)   // 320 window entries (need 319)

typedef float v2f __attribute__((ext_vector_type(2)));

__global__ __launch_bounds__(TPB) void snake_partial(
    const float2* __restrict__ x, const float2* __restrict__ tgt,
    float* __restrict__ partial) {
  const int b   = blockIdx.x;
  const int jg  = blockIdx.y;
  const int tid = threadIdx.x;
  const int j0  = jg * JLEN;

  // t4[w] = (t[w].x, t[w+1].x, t[w].y, t[w+1].y), t[w] = tgt[b][(kb+w)%N].
  __shared__ float4 t4[TWIN];
  const float2* tb = tgt + b * NPT;
  const int kb = (j0 - 255) & (NPT - 1);
  for (int w = tid; w < TWIN; w += TPB) {
    const float2 a = tb[(kb + w) & (NPT - 1)];
    const float2 c = tb[(kb + w + 1) & (NPT - 1)];
    t4[w] = make_float4(a.x, c.x, a.y, c.y);
  }
  __syncthreads();

  // x chunk base per group: cg = (j0 + 256g) % N; chunks never wrap (64-long,
  // 64-aligned). Uniform addresses -> scalar loads, no LDS/VMEM-lane traffic.
  const float4* xg[G];
#pragma unroll
  for (int g = 0; g < G; ++g) {
    const int cg = (j0 + 256 * g) & (NPT - 1);
    xg[g] = (const float4*)(x + b * NPT + cg);
  }

  v2f acc[G];
#pragma unroll
  for (int g = 0; g < G; ++g) acc[g] = (v2f){0.f, 0.f};

  const int off0 = 255 - tid;  // t4[off0+jl] covers j=j0+jl, j0+jl+1 at shift tid
#pragma unroll 4
  for (int jl = 0; jl < JLEN; jl += 2) {
    const float4 tp = t4[off0 + jl];       // one b128 shared by 4 shift groups
    const v2f Tx = {tp.x, tp.y};           // (t_j.x,  t_j1.x)
    const v2f Ty = {tp.z, tp.w};           // (t_j.y,  t_j1.y)
#pragma unroll
    for (int g = 0; g < G; ++g) {
      const float4 xp = xg[g][jl >> 1];    // uniform: s_load_dwordx4
      const v2f Xx = {xp.x, xp.z};
      const v2f Xy = {xp.y, xp.w};
      const v2f dX = Xx - Tx;              // v_pk_add_f32 (neg)
      const v2f dY = Xy - Ty;
      const v2f ss = __builtin_elementwise_fma(dX, dX, dY * dY);
      acc[g] += (v2f){__builtin_amdgcn_sqrtf(ss.x),
                      __builtin_amdgcn_sqrtf(ss.y)};
    }
  }

  float* prow = partial + (jg * BATCH + b) * NPT;  // s innermost: coalesced
#pragma unroll
  for (int g = 0; g < G; ++g)
    prow[tid + 256 * g] = acc[g].x + acc[g].y;
}

// grid (BATCH, 4): thread owns shift s = sg*256+tid; sum 16 jg-partials,
// block-min over 256 shifts -> bmin2[b*4+sg]. Plain stores only.
__global__ __launch_bounds__(TPB) void snake_min(
    const float* __restrict__ partial, float* __restrict__ bmin2) {
  const int b   = blockIdx.x;
  const int sg  = blockIdx.y;
  const int tid = threadIdx.x;
  const int s   = sg * TPB + tid;
  float tot = 0.f;
#pragma unroll
  for (int jg = 0; jg < JGRP; ++jg)
    tot += partial[(jg * BATCH + b) * NPT + s];
  float m = tot;
  for (int o = 32; o > 0; o >>= 1)
    m = fminf(m, __shfl_down(m, o));
  __shared__ float red[4];
  if ((tid & 63) == 0) red[tid >> 6] = m;
  __syncthreads();
  if (tid == 0)
    bmin2[b * 4 + sg] = fminf(fminf(red[0], red[1]), fminf(red[2], red[3]));
}

__global__ void snake_final(const float* __restrict__ bmin2,
                            float* __restrict__ out) {
  const int b = threadIdx.x;  // 64 threads = 1 wave
  const float4 bm = ((const float4*)bmin2)[b];
  float v = fminf(fminf(bm.x, bm.y), fminf(bm.z, bm.w));
  for (int o = 32; o > 0; o >>= 1)
    v += __shfl_down(v, o);
  if (b == 0)
    out[0] = v * (1.0f / ((float)NPT * (float)BATCH));
}

extern "C" void kernel_launch(void* const* d_in, const int* in_sizes, int n_in,
                              void* d_out, int out_size, void* d_ws, size_t ws_size,
                              hipStream_t stream) {
  const float2* x   = (const float2*)d_in[0];
  const float2* tgt = (const float2*)d_in[1];
  float* partial = (float*)d_ws;                   // 16*64*1024 floats = 4 MB
  float* bmin2   = partial + JGRP * BATCH * NPT;   // 256 floats
  float* out     = (float*)d_out;

  dim3 g1(BATCH, JGRP);
  snake_partial<<<g1, TPB, 0, stream>>>(x, tgt, partial);
  dim3 g2(BATCH, 4);
  snake_min<<<g2, TPB, 0, stream>>>(partial, bmin2);
  snake_final<<<1, 64, 0, stream>>>(bmin2, out);
}